// Round 11
// baseline (61.918 us; speedup 1.0000x reference)
//
#include <hip/hip_runtime.h>
#include <hip/hip_bf16.h>

#define BATCH 32
#define SEQ   1024
#define DCH   256
#define TMAX  4096
#define MROWS (BATCH * SEQ)
#define EPS   1e-5f

typedef __attribute__((ext_vector_type(8))) short s16x8;   // 8 bf16 in 4 VGPRs
typedef __attribute__((ext_vector_type(4))) float f32x4;

#define NSTEPS 24
// Wp layout: [s][wv][nc][lane] 16B chunks -> short offset
//   s*8192 + wv*2048 + nc*512 + lane*8      (lane = q*16+cl)
#define WP_SHORTS (NSTEPS * 8192)            // 393216 B / layer

// LDS map (conv path, M=64):
//   phase A: X tile [0, 34816) : 68 rows x 512 B (row xi <-> m0-2+xi), XOR-swz
//   phase B (X dead): red1 [0,2560); stats1 [2560,3200)
//                     h1 [4096, 38944) : 66 rows x 528 B bf16 (padded stride)
//   phase C: red2 [0,2048); stats2 [2048,2560); wred [2560,3584)
#define XROWS      68
#define H1_OFF     4096
#define H1_STRIDE  528
#define STATS1_OFF 2560
#define STATS2_OFF 2048
#define WRED_OFF   2560
#define LDS_TOTAL  38944

#define CONV_BLOCKS 512                      // M=64 rows each
#define REG_BLOCKS  2048
#define GRID_TOTAL  (CONV_BLOCKS + REG_BLOCKS)   // conv first

// truncating f32->bf16 (1 VALU op); fine at this tolerance
__device__ __forceinline__ short f2bf_t(float f) {
    union { float f; unsigned u; } x; x.f = f;
    return (short)(x.u >> 16);
}
// RNE f32->bf16 (weights, one-time prep)
__device__ __forceinline__ short f2bf(float f) {
    union { float f; unsigned u; } x; x.f = f;
    unsigned r = x.u + 0x7fffu + ((x.u >> 16) & 1u);
    return (short)(r >> 16);
}

__device__ __forceinline__ void nt_store4(float* p, float4 v) {
    f32x4 t; t[0] = v.x; t[1] = v.y; t[2] = v.z; t[3] = v.w;
    __builtin_nontemporal_store(t, (f32x4*)p);
}

// ---------------------------------------------------------------------------
// Prep: blocks 0..47 -> weight bf16 repack; blocks 48..79 -> cumsum(target+1)
// + direct scatter of idx[B][TMAX] (frame -> source row, -1 past the end).
// ---------------------------------------------------------------------------
__global__ __launch_bounds__(256) void prep_kernel(
    const float* __restrict__ W1, const float* __restrict__ W2,
    short* __restrict__ Wp1, short* __restrict__ Wp2,
    const int* __restrict__ target, int* __restrict__ idx)
{
    const int bx  = blockIdx.x;
    const int tid = threadIdx.x;
    if (bx < 48) {
        const int s = bx % NSTEPS;
        const float* W = (bx < NSTEPS) ? W1 : W2;
        short* out = (bx < NSTEPS) ? Wp1 : Wp2;
        const int n  = tid;                  // output col 0..255
        const int wv = n >> 6;
        const int nc = (n >> 4) & 3;
        const int cl = n & 15;
        const int ko = s >> 3;
        const int cb = (s & 7) * 32;
        #pragma unroll
        for (int q = 0; q < 4; ++q) {
            short v[8];
            #pragma unroll
            for (int j = 0; j < 8; ++j)
                v[j] = f2bf(W[(size_t)(ko * 256 + cb + q * 8 + j) * 256 + n]);
            short* dst = out + s * 8192 + wv * 2048 + nc * 512 + (q * 16 + cl) * 8;
            *(s16x8*)dst = *(const s16x8*)v;
        }
    } else {
        const int b = bx - 48;
        const int base = tid * 4;            // source pos within batch
        int reps[4], vals[4];
        int s = 0;
        #pragma unroll
        for (int j = 0; j < 4; ++j) {
            reps[j] = target[b * SEQ + base + j] + 1;  // alpha==1.0
            s += reps[j];
            vals[j] = s;
        }
        const int lane = tid & 63;
        int tot = s;
        #pragma unroll
        for (int off = 1; off < 64; off <<= 1) {
            int t = __shfl_up(tot, off, 64);
            if (lane >= off) tot += t;
        }
        __shared__ int wsum[4];
        const int wid = tid >> 6;
        if (lane == 63) wsum[wid] = tot;
        __syncthreads();
        int woff = 0;
        for (int w = 0; w < wid; ++w) woff += wsum[w];
        const int total = wsum[0] + wsum[1] + wsum[2] + wsum[3];
        const int thr_excl = tot - s + woff;
        int* ib = idx + b * TMAX;
        #pragma unroll
        for (int j = 0; j < 4; ++j) {
            const int end   = thr_excl + vals[j];
            const int start = end - reps[j];
            for (int t = start; t < end; ++t) ib[t] = base + j;
        }
        for (int t = total + tid; t < TMAX; t += 256) ib[t] = -1;
    }
}

// GEMM1 step: consume buffer P at K-step S (MFMA cluster under setprio)
#define G1_STEP(P, S)                                                         \
    {                                                                         \
        const int ko_  = (S) >> 3;                                            \
        const int chb_ = ((S) & 7) * 4 + q;                                   \
        __builtin_amdgcn_s_setprio(1);                                        \
        _Pragma("unroll")                                                     \
        for (int mr = 0; mr < 5; ++mr) {                                      \
            int tr = mr * 16 + cl + ko_;                                      \
            if (mr == 4) tr = (tr < XROWS - 1) ? tr : (XROWS - 1);            \
            const s16x8 a = *(const s16x8*)(Xst + tr * 512 +                  \
                                            ((chb_ ^ (tr & 7)) << 4));        \
            _Pragma("unroll")                                                 \
            for (int nc = 0; nc < 4; ++nc)                                    \
                acc1[mr][nc] = __builtin_amdgcn_mfma_f32_16x16x32_bf16(       \
                    a, P[nc], acc1[mr][nc], 0, 0, 0);                         \
        }                                                                     \
        __builtin_amdgcn_s_setprio(0);                                        \
    }

// GEMM2 step
#define G2_STEP(P, S)                                                         \
    {                                                                         \
        const int ko_  = (S) >> 3;                                            \
        const int chb_ = ((S) & 7) * 4 + q;                                   \
        __builtin_amdgcn_s_setprio(1);                                        \
        _Pragma("unroll")                                                     \
        for (int mr = 0; mr < 4; ++mr) {                                      \
            const int tr = mr * 16 + cl + ko_;                                \
            const s16x8 a = *(const s16x8*)(lds + H1_OFF + tr * H1_STRIDE +   \
                                            chb_ * 16);                       \
            _Pragma("unroll")                                                 \
            for (int nc = 0; nc < 4; ++nc)                                    \
                acc2[mr][nc] = __builtin_amdgcn_mfma_f32_16x16x32_bf16(       \
                    a, P[nc], acc2[mr][nc], 0, 0, 0);                         \
        }                                                                     \
        __builtin_amdgcn_s_setprio(0);                                        \
    }

// ---------------------------------------------------------------------------
// Mega-fused kernel, M=64 conv tiles:
//   blocks [0,512):    conv1+LN+ReLU (h1 in LDS) -> conv2+LN+ReLU+head -> dur
//   blocks [512,2560): length-regulate via precomputed idx (pure streaming)
// ---------------------------------------------------------------------------
__global__ __launch_bounds__(256, 3) void fused_kernel(
    const float* __restrict__ enc,      // [MROWS][256] f32
    const float* __restrict__ mask,     // [MROWS]
    const short* __restrict__ Wp1,      // repacked bf16 weights, layer 1
    const short* __restrict__ Wp2,      // layer 2
    const float* __restrict__ b1, const float* __restrict__ g1, const float* __restrict__ be1,
    const float* __restrict__ b2, const float* __restrict__ g2, const float* __restrict__ be2,
    const float* __restrict__ Wl, const float* __restrict__ bl,
    float* __restrict__ out_dur,        // [MROWS]
    const int*  __restrict__ idx,       // [BATCH][TMAX]
    float* __restrict__ out_main,       // [BATCH][TMAX][256]
    float* __restrict__ out_pos)        // [BATCH][TMAX]
{
    __shared__ __align__(16) char lds[LDS_TOTAL];
    const int tid = threadIdx.x;
    const int bx  = blockIdx.x;

    if (bx >= CONV_BLOCKS) {
        // ====== length-regulate block: no LDS, no barriers ======
        const int r  = bx - CONV_BLOCKS;           // 0..2047
        const int b  = r >> 6;
        const int t0 = (r & 63) * 64;
        const int f4 = (tid & 63) * 4;
        const int rg = tid >> 6;
        if (tid < 64) {
            const int t  = t0 + tid;
            const int si = idx[b * TMAX + t];
            __builtin_nontemporal_store((si >= 0) ? (float)(t + 1) : 0.f,
                                        out_pos + b * TMAX + t);
        }
        #pragma unroll
        for (int g = 0; g < 16; ++g) {
            const int tt = g * 4 + rg;
            const int si = idx[b * TMAX + t0 + tt];   // wave-uniform -> broadcast
            float4 v = make_float4(0.f, 0.f, 0.f, 0.f);
            if (si >= 0)
                v = *reinterpret_cast<const float4*>(enc + (size_t)(b * SEQ + si) * 256 + f4);
            nt_store4(out_main + (size_t)(b * TMAX + t0 + tt) * 256 + f4, v);
        }
        return;
    }

    // ======================= conv block (64 rows) =======================
    char* const Xst = lds;

    const int lane = tid & 63;
    const int wv   = tid >> 6;          // wave 0..3 -> cols wv*64..+63
    const int cl   = lane & 15;
    const int q    = lane >> 4;
    const int m0   = bx * 64;
    const int blo  = m0 & ~(SEQ - 1);
    const int bhi  = blo + SEQ;

    // ---- stage X tile: rows m0-2 .. m0+65 (xi 0..67), XOR-swz chunks ----
    for (int t = tid; t < XROWS * 32; t += 256) {
        const int r  = t >> 5;
        const int ch = t & 31;
        const int grow = m0 - 2 + r;
        s16x8 v = {0, 0, 0, 0, 0, 0, 0, 0};
        if (grow >= blo && grow < bhi) {
            const float* xf = enc + (size_t)grow * DCH + ch * 8;
            const float4 f0 = *(const float4*)xf;
            const float4 f1 = *(const float4*)(xf + 4);
            const float mk = mask[grow];
            v[0] = f2bf_t(f0.x * mk); v[1] = f2bf_t(f0.y * mk);
            v[2] = f2bf_t(f0.z * mk); v[3] = f2bf_t(f0.w * mk);
            v[4] = f2bf_t(f1.x * mk); v[5] = f2bf_t(f1.y * mk);
            v[6] = f2bf_t(f1.z * mk); v[7] = f2bf_t(f1.w * mk);
        }
        *(s16x8*)(Xst + r * 512 + ((ch ^ (r & 7)) << 4)) = v;
    }

    // ---- GEMM1 acc init with bias1 ----
    f32x4 acc1[5][4];
    #pragma unroll
    for (int nc = 0; nc < 4; ++nc) {
        const float b = b1[wv * 64 + nc * 16 + cl];
        #pragma unroll
        for (int mr = 0; mr < 5; ++mr) acc1[mr][nc] = (f32x4){b, b, b, b};
    }

    const short* wb1 = Wp1 + wv * 2048 + lane * 8;
    const short* wb2 = Wp2 + wv * 2048 + lane * 8;
    // alternating prefetch buffers: p0 = even steps, p1 = odd steps
    s16x8 p0[4], p1[4];
    #pragma unroll
    for (int nc = 0; nc < 4; ++nc) {
        p0[nc] = *(const s16x8*)(wb1 + nc * 512);
        p1[nc] = *(const s16x8*)(wb1 + 8192 + nc * 512);
    }

    __syncthreads();   // X tile ready

    // ---- GEMM1 K loop: manual unroll-2, zero buffer copies ----
    for (int s = 0; s < NSTEPS; s += 2) {
        G1_STEP(p0, s)
        if (s + 2 < NSTEPS) {
            #pragma unroll
            for (int nc = 0; nc < 4; ++nc)
                p0[nc] = *(const s16x8*)(wb1 + (s + 2) * 8192 + nc * 512);
        }
        G1_STEP(p1, s + 1)
        if (s + 3 < NSTEPS) {
            #pragma unroll
            for (int nc = 0; nc < 4; ++nc)
                p1[nc] = *(const s16x8*)(wb1 + (s + 3) * 8192 + nc * 512);
        }
    }

    // ---- LN1 stats (h1 rows hr < 66; hr -> global m0-1+hr) ----
    float* red1 = (float*)lds;
    float* st1  = (float*)(lds + STATS1_OFF);
    __syncthreads();   // all waves done reading X
    #pragma unroll
    for (int mr = 0; mr < 5; ++mr) {
        #pragma unroll
        for (int rg = 0; rg < 4; ++rg) {
            float s1 = 0.f, s2 = 0.f;
            #pragma unroll
            for (int nc = 0; nc < 4; ++nc) {
                const float v = acc1[mr][nc][rg];
                s1 += v; s2 += v * v;
            }
            #pragma unroll
            for (int m = 1; m < 16; m <<= 1) {
                s1 += __shfl_xor(s1, m, 64);
                s2 += __shfl_xor(s2, m, 64);
            }
            const int hr = mr * 16 + q * 4 + rg;
            if (cl == 0 && hr < 66) {
                red1[(hr * 4 + wv) * 2]     = s1;
                red1[(hr * 4 + wv) * 2 + 1] = s2;
            }
        }
    }
    __syncthreads();
    if (tid < 66) {
        const float s1 = red1[tid*8] + red1[tid*8+2] + red1[tid*8+4] + red1[tid*8+6];
        const float s2 = red1[tid*8+1] + red1[tid*8+3] + red1[tid*8+5] + red1[tid*8+7];
        const float mean = s1 * (1.f / 256.f);
        const float var  = s2 * (1.f / 256.f) - mean * mean;
        st1[tid * 2]     = mean;
        st1[tid * 2 + 1] = rsqrtf(var + EPS);
    }
    __syncthreads();

    // ---- write h1 (LN+ReLU, bf16) into LDS (padded stride, no XOR) ----
    {
        float gv[4], bv[4];
        #pragma unroll
        for (int nc = 0; nc < 4; ++nc) {
            const int col = wv * 64 + nc * 16 + cl;
            gv[nc] = g1[col]; bv[nc] = be1[col];
        }
        #pragma unroll
        for (int mr = 0; mr < 5; ++mr) {
            #pragma unroll
            for (int rg = 0; rg < 4; ++rg) {
                const int hr = mr * 16 + q * 4 + rg;
                if (hr < 66) {
                    const int grow = m0 - 1 + hr;
                    const bool inb = (grow >= blo) && (grow < bhi);
                    const float2 ms = *(const float2*)(st1 + hr * 2);
                    #pragma unroll
                    for (int nc = 0; nc < 4; ++nc) {
                        const int col = wv * 64 + nc * 16 + cl;
                        float v = (acc1[mr][nc][rg] - ms.x) * ms.y * gv[nc] + bv[nc];
                        v = inb ? fmaxf(v, 0.f) : 0.f;
                        *(short*)(lds + H1_OFF + hr * H1_STRIDE + col * 2) = f2bf_t(v);
                    }
                }
            }
        }
    }
    // prefetch GEMM2 step 0/1 B frags (hide L2 latency in barrier window)
    s16x8 q0[4], q1[4];
    #pragma unroll
    for (int nc = 0; nc < 4; ++nc) {
        q0[nc] = *(const s16x8*)(wb2 + nc * 512);
        q1[nc] = *(const s16x8*)(wb2 + 8192 + nc * 512);
    }
    __syncthreads();   // h1 ready

    // ---- GEMM2 K loop (A from h1 LDS rows 0..65) ----
    f32x4 acc2[4][4];
    #pragma unroll
    for (int nc = 0; nc < 4; ++nc) {
        const float b = b2[wv * 64 + nc * 16 + cl];
        #pragma unroll
        for (int mr = 0; mr < 4; ++mr) acc2[mr][nc] = (f32x4){b, b, b, b};
    }
    for (int s = 0; s < NSTEPS; s += 2) {
        G2_STEP(q0, s)
        if (s + 2 < NSTEPS) {
            #pragma unroll
            for (int nc = 0; nc < 4; ++nc)
                q0[nc] = *(const s16x8*)(wb2 + (s + 2) * 8192 + nc * 512);
        }
        G2_STEP(q1, s + 1)
        if (s + 3 < NSTEPS) {
            #pragma unroll
            for (int nc = 0; nc < 4; ++nc)
                q1[nc] = *(const s16x8*)(wb2 + (s + 3) * 8192 + nc * 512);
        }
    }

    // ---- LN2 stats (rows 0..63 = global m0..m0+63) ----
    float* red2 = (float*)lds;
    float* st2  = (float*)(lds + STATS2_OFF);
    float* wred = (float*)(lds + WRED_OFF);
    __syncthreads();   // all waves done with GEMM2
    #pragma unroll
    for (int mr = 0; mr < 4; ++mr) {
        #pragma unroll
        for (int rg = 0; rg < 4; ++rg) {
            float s1 = 0.f, s2 = 0.f;
            #pragma unroll
            for (int nc = 0; nc < 4; ++nc) {
                const float v = acc2[mr][nc][rg];
                s1 += v; s2 += v * v;
            }
            #pragma unroll
            for (int m = 1; m < 16; m <<= 1) {
                s1 += __shfl_xor(s1, m, 64);
                s2 += __shfl_xor(s2, m, 64);
            }
            if (cl == 0) {
                const int r = mr * 16 + q * 4 + rg;
                red2[(r * 4 + wv) * 2]     = s1;
                red2[(r * 4 + wv) * 2 + 1] = s2;
            }
        }
    }
    __syncthreads();
    if (tid < 64) {
        const float s1 = red2[tid*8] + red2[tid*8+2] + red2[tid*8+4] + red2[tid*8+6];
        const float s2 = red2[tid*8+1] + red2[tid*8+3] + red2[tid*8+5] + red2[tid*8+7];
        const float mean = s1 * (1.f / 256.f);
        const float var  = s2 * (1.f / 256.f) - mean * mean;
        st2[tid * 2]     = mean;
        st2[tid * 2 + 1] = rsqrtf(var + EPS);
    }
    __syncthreads();

    // ---- head: relu(LN2) . Wl + bl, masked, relu -> dur ----
    {
        float gv[4], bv[4], wl[4];
        #pragma unroll
        for (int nc = 0; nc < 4; ++nc) {
            const int col = wv * 64 + nc * 16 + cl;
            gv[nc] = g2[col]; bv[nc] = be2[col]; wl[nc] = Wl[col];
        }
        #pragma unroll
        for (int mr = 0; mr < 4; ++mr) {
            #pragma unroll
            for (int rg = 0; rg < 4; ++rg) {
                const int r = mr * 16 + q * 4 + rg;
                const float2 ms = *(const float2*)(st2 + r * 2);
                float p = 0.f;
                #pragma unroll
                for (int nc = 0; nc < 4; ++nc) {
                    float v = (acc2[mr][nc][rg] - ms.x) * ms.y * gv[nc] + bv[nc];
                    p += fmaxf(v, 0.f) * wl[nc];
                }
                #pragma unroll
                for (int m = 1; m < 16; m <<= 1) p += __shfl_xor(p, m, 64);
                if (cl == 0) wred[r * 4 + wv] = p;
            }
        }
        __syncthreads();
        if (tid < 64) {
            float d = wred[tid*4] + wred[tid*4+1] + wred[tid*4+2] + wred[tid*4+3] + bl[0];
            d *= mask[m0 + tid];
            out_dur[m0 + tid] = fmaxf(d, 0.f);
        }
    }
}

// ---------------------------------------------------------------------------
extern "C" void kernel_launch(void* const* d_in, const int* in_sizes, int n_in,
                              void* d_out, int out_size, void* d_ws, size_t ws_size,
                              hipStream_t stream) {
    const float* enc   = (const float*)d_in[0];
    const float* mask  = (const float*)d_in[1];
    const int*   target= (const int*)  d_in[2];
    const float* W1    = (const float*)d_in[4];
    const float* b1    = (const float*)d_in[5];
    const float* g1    = (const float*)d_in[6];
    const float* beta1 = (const float*)d_in[7];
    const float* W2    = (const float*)d_in[8];
    const float* b2    = (const float*)d_in[9];
    const float* g2    = (const float*)d_in[10];
    const float* beta2 = (const float*)d_in[11];
    const float* Wl    = (const float*)d_in[12];
    const float* bl    = (const float*)d_in[13];

    float* outF = (float*)d_out;
    float* out_main = outF;                               // 32*4096*256
    float* out_pos  = outF + (size_t)BATCH * TMAX * DCH;  // 32*4096
    float* out_dur  = out_pos + (size_t)BATCH * TMAX;     // 32*1024

    char* ws = (char*)d_ws;
    short* Wp1 = (short*)ws;
    short* Wp2 = Wp1 + WP_SHORTS;
    int*   idx = (int*)(Wp2 + WP_SHORTS);                 // [BATCH][TMAX]

    prep_kernel<<<80, 256, 0, stream>>>(W1, W2, Wp1, Wp2, target, idx);
    fused_kernel<<<GRID_TOTAL, 256, 0, stream>>>(
        enc, mask, Wp1, Wp2,
        b1, g1, beta1, b2, g2, beta2, Wl, bl,
        out_dur, idx, out_main, out_pos);
}

// Round 12
// 55.808 us; speedup vs baseline: 1.1095x; 1.1095x over previous
//
#include <hip/hip_runtime.h>
#include <hip/hip_bf16.h>

#define BATCH 32
#define SEQ   1024
#define DCH   256
#define TMAX  4096
#define MROWS (BATCH * SEQ)
#define EPS   1e-5f

typedef __attribute__((ext_vector_type(8))) short s16x8;   // 8 bf16 in 4 VGPRs
typedef __attribute__((ext_vector_type(4))) float f32x4;

#define NSTEPS 24
// Wp layout: [s][wv][nc][lane] 16B chunks -> short offset
#define WP_SHORTS (NSTEPS * 8192)            // 393216 B / layer

// LDS map (conv path, M=64). Regions overlay across dead phases:
//   phase A: X tile [0, 34816) : 68 rows x 512 B (xi <-> m0-2+xi), XOR-swz
//   phase B (X dead):    LN1 partials [0, 33792) = [66 rows][64 lanes][2] f32
//   phase C:             h1 [4096, 38944) : 66 rows x 528 B bf16
//   phase D (h1 dead):   LN2 partials [0, 32768) = [64][64][2] f32
//   phase E (red dead):  head partials [0, 16384) = [64][64] f32
//   stats (mean,rstd):   [38944, 39472)  (written LN1, reused LN2)
#define XROWS      68
#define H1_OFF     4096
#define H1_STRIDE  528
#define ST_OFF     38944
#define LDS_TOTAL  39472                     // 4 blocks/CU by LDS

#define CONV_BLOCKS 512                      // M=64 rows each
#define REG_BLOCKS  2048
#define GRID_TOTAL  (CONV_BLOCKS + REG_BLOCKS)   // conv first

// truncating f32->bf16 (1 VALU op); fine at this tolerance
__device__ __forceinline__ short f2bf_t(float f) {
    union { float f; unsigned u; } x; x.f = f;
    return (short)(x.u >> 16);
}
// RNE f32->bf16 (weights, one-time prep)
__device__ __forceinline__ short f2bf(float f) {
    union { float f; unsigned u; } x; x.f = f;
    unsigned r = x.u + 0x7fffu + ((x.u >> 16) & 1u);
    return (short)(r >> 16);
}

// ---------------------------------------------------------------------------
// Prep: blocks 0..47 -> weight bf16 repack; blocks 48..79 -> cumsum(target+1)
// + direct scatter of idx[B][TMAX] (frame -> source row, -1 past the end).
// ---------------------------------------------------------------------------
__global__ __launch_bounds__(256) void prep_kernel(
    const float* __restrict__ W1, const float* __restrict__ W2,
    short* __restrict__ Wp1, short* __restrict__ Wp2,
    const int* __restrict__ target, int* __restrict__ idx)
{
    const int bx  = blockIdx.x;
    const int tid = threadIdx.x;
    if (bx < 48) {
        const int s = bx % NSTEPS;
        const float* W = (bx < NSTEPS) ? W1 : W2;
        short* out = (bx < NSTEPS) ? Wp1 : Wp2;
        const int n  = tid;                  // output col 0..255
        const int wv = n >> 6;
        const int nc = (n >> 4) & 3;
        const int cl = n & 15;
        const int ko = s >> 3;
        const int cb = (s & 7) * 32;
        #pragma unroll
        for (int q = 0; q < 4; ++q) {
            short v[8];
            #pragma unroll
            for (int j = 0; j < 8; ++j)
                v[j] = f2bf(W[(size_t)(ko * 256 + cb + q * 8 + j) * 256 + n]);
            short* dst = out + s * 8192 + wv * 2048 + nc * 512 + (q * 16 + cl) * 8;
            *(s16x8*)dst = *(const s16x8*)v;
        }
    } else {
        const int b = bx - 48;
        const int base = tid * 4;            // source pos within batch
        int reps[4], vals[4];
        int s = 0;
        #pragma unroll
        for (int j = 0; j < 4; ++j) {
            reps[j] = target[b * SEQ + base + j] + 1;  // alpha==1.0
            s += reps[j];
            vals[j] = s;
        }
        const int lane = tid & 63;
        int tot = s;
        #pragma unroll
        for (int off = 1; off < 64; off <<= 1) {
            int t = __shfl_up(tot, off, 64);
            if (lane >= off) tot += t;
        }
        __shared__ int wsum[4];
        const int wid = tid >> 6;
        if (lane == 63) wsum[wid] = tot;
        __syncthreads();
        int woff = 0;
        for (int w = 0; w < wid; ++w) woff += wsum[w];
        const int total = wsum[0] + wsum[1] + wsum[2] + wsum[3];
        const int thr_excl = tot - s + woff;
        int* ib = idx + b * TMAX;
        #pragma unroll
        for (int j = 0; j < 4; ++j) {
            const int end   = thr_excl + vals[j];
            const int start = end - reps[j];
            for (int t = start; t < end; ++t) ib[t] = base + j;
        }
        for (int t = total + tid; t < TMAX; t += 256) ib[t] = -1;
    }
}

// ---------------------------------------------------------------------------
// Mega-fused kernel, M=64 conv tiles:
//   blocks [0,512):    conv1+LN+ReLU (h1 in LDS) -> conv2+LN+ReLU+head -> dur
//   blocks [512,2560): length-regulate via precomputed idx (pure streaming)
// ---------------------------------------------------------------------------
__global__ __launch_bounds__(256, 3) void fused_kernel(
    const float* __restrict__ enc,      // [MROWS][256] f32
    const float* __restrict__ mask,     // [MROWS]
    const short* __restrict__ Wp1,      // repacked bf16 weights, layer 1
    const short* __restrict__ Wp2,      // layer 2
    const float* __restrict__ b1, const float* __restrict__ g1, const float* __restrict__ be1,
    const float* __restrict__ b2, const float* __restrict__ g2, const float* __restrict__ be2,
    const float* __restrict__ Wl, const float* __restrict__ bl,
    float* __restrict__ out_dur,        // [MROWS]
    const int*  __restrict__ idx,       // [BATCH][TMAX]
    float* __restrict__ out_main,       // [BATCH][TMAX][256]
    float* __restrict__ out_pos)        // [BATCH][TMAX]
{
    __shared__ __align__(16) char lds[LDS_TOTAL];
    const int tid = threadIdx.x;
    const int bx  = blockIdx.x;

    if (bx >= CONV_BLOCKS) {
        // =================== length-regulate block ===================
        const int r  = bx - CONV_BLOCKS;           // 0..2047
        const int b  = r >> 6;
        const int t0 = (r & 63) * 64;
        int* sidx = (int*)lds;
        if (tid < 64) {
            const int t  = t0 + tid;
            const int si = idx[b * TMAX + t];
            sidx[tid] = si;
            out_pos[b * TMAX + t] = (si >= 0) ? (float)(t + 1) : 0.f;
        }
        __syncthreads();
        const int f4 = (tid & 63) * 4;
        const int rg = tid >> 6;
        #pragma unroll
        for (int g = 0; g < 16; ++g) {
            const int tt = g * 4 + rg;
            const int si = sidx[tt];
            float4 v = make_float4(0.f, 0.f, 0.f, 0.f);
            if (si >= 0)
                v = *reinterpret_cast<const float4*>(enc + (size_t)(b * SEQ + si) * 256 + f4);
            *reinterpret_cast<float4*>(out_main + (size_t)(b * TMAX + t0 + tt) * 256 + f4) = v;
        }
        return;
    }

    // ======================= conv block (64 rows) =======================
    char* const Xst = lds;

    const int lane = tid & 63;
    const int wv   = tid >> 6;          // wave 0..3 -> cols wv*64..+63
    const int cl   = lane & 15;
    const int q    = lane >> 4;
    const int m0   = bx * 64;
    const int blo  = m0 & ~(SEQ - 1);
    const int bhi  = blo + SEQ;
    const int li   = wv * 16 + cl;      // partial-lane index 0..63

    // ---- stage X tile: rows m0-2 .. m0+65 (xi 0..67), XOR-swz chunks ----
    for (int t = tid; t < XROWS * 32; t += 256) {
        const int r  = t >> 5;
        const int ch = t & 31;
        const int grow = m0 - 2 + r;
        s16x8 v = {0, 0, 0, 0, 0, 0, 0, 0};
        if (grow >= blo && grow < bhi) {
            const float* xf = enc + (size_t)grow * DCH + ch * 8;
            const float4 f0 = *(const float4*)xf;
            const float4 f1 = *(const float4*)(xf + 4);
            const float mk = mask[grow];
            v[0] = f2bf_t(f0.x * mk); v[1] = f2bf_t(f0.y * mk);
            v[2] = f2bf_t(f0.z * mk); v[3] = f2bf_t(f0.w * mk);
            v[4] = f2bf_t(f1.x * mk); v[5] = f2bf_t(f1.y * mk);
            v[6] = f2bf_t(f1.z * mk); v[7] = f2bf_t(f1.w * mk);
        }
        *(s16x8*)(Xst + r * 512 + ((ch ^ (r & 7)) << 4)) = v;
    }

    // ---- GEMM1 acc init with bias1 ----
    f32x4 acc1[5][4];
    #pragma unroll
    for (int nc = 0; nc < 4; ++nc) {
        const float b = b1[wv * 64 + nc * 16 + cl];
        #pragma unroll
        for (int mr = 0; mr < 5; ++mr) acc1[mr][nc] = (f32x4){b, b, b, b};
    }

    const short* wb1 = Wp1 + wv * 2048 + lane * 8;
    const short* wb2 = Wp2 + wv * 2048 + lane * 8;
    // depth-2 B prefetch: p0 = step s, p1 = step s+1
    s16x8 p0[4], p1[4];
    #pragma unroll
    for (int nc = 0; nc < 4; ++nc) {
        p0[nc] = *(const s16x8*)(wb1 + nc * 512);
        p1[nc] = *(const s16x8*)(wb1 + 8192 + nc * 512);
    }

    __syncthreads();   // X tile ready

    // ---- GEMM1 K loop (depth-2 B prefetch) ----
    for (int s = 0; s < NSTEPS; ++s) {
        const int sp = (s + 2 < NSTEPS) ? s + 2 : s;
        s16x8 bn[4];
        #pragma unroll
        for (int nc = 0; nc < 4; ++nc)
            bn[nc] = *(const s16x8*)(wb1 + sp * 8192 + nc * 512);
        const int ko  = s >> 3;
        const int chb = (s & 7) * 4 + q;
        #pragma unroll
        for (int mr = 0; mr < 5; ++mr) {
            int tr = mr * 16 + cl + ko;              // X row xi
            if (mr == 4) tr = (tr < XROWS - 1) ? tr : (XROWS - 1);  // junk rows clamp
            const s16x8 a = *(const s16x8*)(Xst + tr * 512 + ((chb ^ (tr & 7)) << 4));
            #pragma unroll
            for (int nc = 0; nc < 4; ++nc)
                acc1[mr][nc] = __builtin_amdgcn_mfma_f32_16x16x32_bf16(
                    a, p0[nc], acc1[mr][nc], 0, 0, 0);
        }
        #pragma unroll
        for (int nc = 0; nc < 4; ++nc) { p0[nc] = p1[nc]; p1[nc] = bn[nc]; }
    }

    // ---- LN1 partials: in-thread nc sum -> one float2 LDS write per row ----
    float* st1 = (float*)(lds + ST_OFF);
    __syncthreads();   // all waves done reading X
    #pragma unroll
    for (int mr = 0; mr < 5; ++mr) {
        #pragma unroll
        for (int rg = 0; rg < 4; ++rg) {
            const int hr = mr * 16 + q * 4 + rg;
            float s1 = 0.f, s2 = 0.f;
            #pragma unroll
            for (int nc = 0; nc < 4; ++nc) {
                const float v = acc1[mr][nc][rg];
                s1 += v; s2 += v * v;
            }
            if (hr < 66)
                *(float2*)(lds + hr * 512 + li * 8) = make_float2(s1, s2);
        }
    }
    __syncthreads();
    if (tid < 66) {
        const char* base = lds + tid * 512;
        float s1 = 0.f, s2 = 0.f;
        #pragma unroll
        for (int k = 0; k < 32; ++k) {
            const int c = ((tid + k) & 31) * 16;    // rotated to spread banks
            const f32x4 v = *(const f32x4*)(base + c);
            s1 += v[0] + v[2];
            s2 += v[1] + v[3];
        }
        const float mean = s1 * (1.f / 256.f);
        const float var  = s2 * (1.f / 256.f) - mean * mean;
        st1[tid * 2]     = mean;
        st1[tid * 2 + 1] = rsqrtf(var + EPS);
    }
    __syncthreads();

    // ---- write h1 (LN+ReLU, bf16) into LDS (padded stride) ----
    {
        float gv[4], bv[4];
        #pragma unroll
        for (int nc = 0; nc < 4; ++nc) {
            const int col = wv * 64 + nc * 16 + cl;
            gv[nc] = g1[col]; bv[nc] = be1[col];
        }
        #pragma unroll
        for (int mr = 0; mr < 5; ++mr) {
            #pragma unroll
            for (int rg = 0; rg < 4; ++rg) {
                const int hr = mr * 16 + q * 4 + rg;
                if (hr < 66) {
                    const int grow = m0 - 1 + hr;
                    const bool inb = (grow >= blo) && (grow < bhi);
                    const float2 ms = *(const float2*)(st1 + hr * 2);
                    #pragma unroll
                    for (int nc = 0; nc < 4; ++nc) {
                        const int col = wv * 64 + nc * 16 + cl;
                        float v = (acc1[mr][nc][rg] - ms.x) * ms.y * gv[nc] + bv[nc];
                        v = inb ? fmaxf(v, 0.f) : 0.f;
                        *(short*)(lds + H1_OFF + hr * H1_STRIDE + col * 2) = f2bf_t(v);
                    }
                }
            }
        }
    }
    // prefetch GEMM2 step 0/1 B frags (hide L2 latency in barrier window)
    s16x8 q0[4], q1[4];
    #pragma unroll
    for (int nc = 0; nc < 4; ++nc) {
        q0[nc] = *(const s16x8*)(wb2 + nc * 512);
        q1[nc] = *(const s16x8*)(wb2 + 8192 + nc * 512);
    }
    __syncthreads();   // h1 ready

    // ---- GEMM2 K loop (A from h1 LDS rows 0..65, depth-2 B prefetch) ----
    f32x4 acc2[4][4];
    #pragma unroll
    for (int nc = 0; nc < 4; ++nc) {
        const float b = b2[wv * 64 + nc * 16 + cl];
        #pragma unroll
        for (int mr = 0; mr < 4; ++mr) acc2[mr][nc] = (f32x4){b, b, b, b};
    }
    for (int s = 0; s < NSTEPS; ++s) {
        const int sp = (s + 2 < NSTEPS) ? s + 2 : s;
        s16x8 bn[4];
        #pragma unroll
        for (int nc = 0; nc < 4; ++nc)
            bn[nc] = *(const s16x8*)(wb2 + sp * 8192 + nc * 512);
        const int ko  = s >> 3;
        const int chb = (s & 7) * 4 + q;
        #pragma unroll
        for (int mr = 0; mr < 4; ++mr) {
            const int tr = mr * 16 + cl + ko;            // h1 row (0..65)
            const s16x8 a = *(const s16x8*)(lds + H1_OFF + tr * H1_STRIDE + chb * 16);
            #pragma unroll
            for (int nc = 0; nc < 4; ++nc)
                acc2[mr][nc] = __builtin_amdgcn_mfma_f32_16x16x32_bf16(
                    a, q0[nc], acc2[mr][nc], 0, 0, 0);
        }
        #pragma unroll
        for (int nc = 0; nc < 4; ++nc) { q0[nc] = q1[nc]; q1[nc] = bn[nc]; }
    }

    // ---- LN2 partials (rows 0..63), same scheme ----
    float* st2 = (float*)(lds + ST_OFF);    // st1 dead
    __syncthreads();   // all waves done with GEMM2 (h1 dead)
    #pragma unroll
    for (int mr = 0; mr < 4; ++mr) {
        #pragma unroll
        for (int rg = 0; rg < 4; ++rg) {
            const int r = mr * 16 + q * 4 + rg;
            float s1 = 0.f, s2 = 0.f;
            #pragma unroll
            for (int nc = 0; nc < 4; ++nc) {
                const float v = acc2[mr][nc][rg];
                s1 += v; s2 += v * v;
            }
            *(float2*)(lds + r * 512 + li * 8) = make_float2(s1, s2);
        }
    }
    __syncthreads();
    if (tid < 64) {
        const char* base = lds + tid * 512;
        float s1 = 0.f, s2 = 0.f;
        #pragma unroll
        for (int k = 0; k < 32; ++k) {
            const int c = ((tid + k) & 31) * 16;
            const f32x4 v = *(const f32x4*)(base + c);
            s1 += v[0] + v[2];
            s2 += v[1] + v[3];
        }
        const float mean = s1 * (1.f / 256.f);
        const float var  = s2 * (1.f / 256.f) - mean * mean;
        st2[tid * 2]     = mean;
        st2[tid * 2 + 1] = rsqrtf(var + EPS);
    }
    __syncthreads();

    // ---- head: relu(LN2) . Wl partials -> LDS -> final reduce ----
    {
        float gv[4], bv[4], wl[4];
        #pragma unroll
        for (int nc = 0; nc < 4; ++nc) {
            const int col = wv * 64 + nc * 16 + cl;
            gv[nc] = g2[col]; bv[nc] = be2[col]; wl[nc] = Wl[col];
        }
        #pragma unroll
        for (int mr = 0; mr < 4; ++mr) {
            #pragma unroll
            for (int rg = 0; rg < 4; ++rg) {
                const int r = mr * 16 + q * 4 + rg;
                const float2 ms = *(const float2*)(st2 + r * 2);
                float p = 0.f;
                #pragma unroll
                for (int nc = 0; nc < 4; ++nc) {
                    float v = (acc2[mr][nc][rg] - ms.x) * ms.y * gv[nc] + bv[nc];
                    p += fmaxf(v, 0.f) * wl[nc];
                }
                *(float*)(lds + r * 256 + li * 4) = p;   // [64][64] f32
            }
        }
        __syncthreads();
        if (tid < 64) {
            const char* base = lds + tid * 256;
            float d = 0.f;
            #pragma unroll
            for (int k = 0; k < 16; ++k) {
                const int c = ((tid + k) & 15) * 16;
                const f32x4 v = *(const f32x4*)(base + c);
                d += (v[0] + v[1]) + (v[2] + v[3]);
            }
            d += bl[0];
            d *= mask[m0 + tid];
            out_dur[m0 + tid] = fmaxf(d, 0.f);
        }
    }
}

// ---------------------------------------------------------------------------
extern "C" void kernel_launch(void* const* d_in, const int* in_sizes, int n_in,
                              void* d_out, int out_size, void* d_ws, size_t ws_size,
                              hipStream_t stream) {
    const float* enc   = (const float*)d_in[0];
    const float* mask  = (const float*)d_in[1];
    const int*   target= (const int*)  d_in[2];
    const float* W1    = (const float*)d_in[4];
    const float* b1    = (const float*)d_in[5];
    const float* g1    = (const float*)d_in[6];
    const float* beta1 = (const float*)d_in[7];
    const float* W2    = (const float*)d_in[8];
    const float* b2    = (const float*)d_in[9];
    const float* g2    = (const float*)d_in[10];
    const float* beta2 = (const float*)d_in[11];
    const float* Wl    = (const float*)d_in[12];
    const float* bl    = (const float*)d_in[13];

    float* outF = (float*)d_out;
    float* out_main = outF;                               // 32*4096*256
    float* out_pos  = outF + (size_t)BATCH * TMAX * DCH;  // 32*4096
    float* out_dur  = out_pos + (size_t)BATCH * TMAX;     // 32*1024

    char* ws = (char*)d_ws;
    short* Wp1 = (short*)ws;
    short* Wp2 = Wp1 + WP_SHORTS;
    int*   idx = (int*)(Wp2 + WP_SHORTS);                 // [BATCH][TMAX]

    prep_kernel<<<80, 256, 0, stream>>>(W1, W2, Wp1, Wp2, target, idx);
    fused_kernel<<<GRID_TOTAL, 256, 0, stream>>>(
        enc, mask, Wp1, Wp2,
        b1, g1, beta1, b2, g2, beta2, Wl, bl,
        out_dur, idx, out_main, out_pos);
}